// Round 15
// baseline (126.970 us; speedup 1.0000x reference)
//
#include <hip/hip_runtime.h>
#include <hip/hip_bf16.h>

// Sizes (fixed by the problem)
#define BATCH 16
#define NQ    1024
#define DM    256
#define NROWS (BATCH * NQ)   // 16384 rows per side
#define RINV  10.0f          // 1/REG

typedef float  f32x4 __attribute__((ext_vector_type(4)));
typedef short  s16x8 __attribute__((ext_vector_type(8)));

static __device__ __forceinline__ ushort f2bf(float f) {
    unsigned u = __builtin_bit_cast(unsigned, f);
    u += 0x7fffu + ((u >> 16) & 1u);
    return (ushort)(u >> 16);
}
static __device__ __forceinline__ float bf2f(ushort h) {
    return __builtin_bit_cast(float, ((unsigned)h) << 16);
}

// Linear-domain Sinkhorn on K~ = exp(-10*cost) stored bf16 (33.5 MB):
//   a = 1/(K~ b),  b = 1/(K~^T a),  plan = a*b*K~,  cost = -0.1*log(K~).
// Base = R14 winner (113.9us): XCD-pinned batches, W-hoisted proj.
// ROUND-15 change: split b-recombination into a tiny k_comb kernel so
// k_sink no longer reads 32 partial strips per block -> sink grid can grow
// to 1024 blocks (4 blocks/CU, 16 waves/CU, 2x latency-hiding TLP). Single
// part buffer; final also reads the combined b directly.
// Lessons kept: no fences/atomics in hot kernels (R8 +25us), no nt stores
// (R10 A/B +14us), no >256-thr blocks for short streaming kernels (R8-R10).

// ---------------------------------------------------------------- P0: pack W
__global__ void __launch_bounds__(256) k_prep(const float* __restrict__ Wq,
                                              const float* __restrict__ Wk,
                                              ushort* __restrict__ wp0,
                                              ushort* __restrict__ wp1) {
    int gid = blockIdx.x * 256 + threadIdx.x;   // 64 blocks -> gid < 16384
    const float* Wsrc = (gid < 8192) ? Wq : Wk;
    ushort* dst = (gid < 8192) ? wp0 : wp1;
    int gx = gid & 8191;
    int gcol = gx >> 9, kk = (gx >> 6) & 7, ln = gx & 63;
    const float* srow = Wsrc + (size_t)(gcol * 16 + (ln & 15)) * DM
                             + kk * 32 + (ln >> 4) * 8;
    ushort* d = dst + (size_t)gx * 8;
#pragma unroll
    for (int e = 0; e < 8; e++) d[e] = f2bf(srow[e]);
}

// ---------------------------------------------------------------- P1: projection
// 512 blocks x 256 thr; 4 x 16-row groups per block; W fragments hoisted to
// registers. XCD pinning: batches {2xcd, 2xcd+1} on XCD xcd.
__global__ void __launch_bounds__(256) k_proj(
        const float* __restrict__ drone, const float* __restrict__ sat,
        const ushort* __restrict__ wp0, const ushort* __restrict__ wp1,
        const float* __restrict__ bq, const float* __restrict__ bk,
        ushort* __restrict__ qkp) {
    __shared__ union {
        float  As[16][260];
        ushort S[16][280];
    } AB;
    __shared__ float red[4][16];

    int t = threadIdx.x;
    int lane = t & 63, w = t >> 6, l16 = lane & 15, lh = lane >> 4;
    int x = blockIdx.x, xcd = x & 7, j = x >> 3;      // j 0..63
    int gbase = (j < 32) ? (xcd * 128 + j * 4)
                         : (1024 + xcd * 128 + (j - 32) * 4);
    const float* xsrc; const ushort* Wp; const float* bias;
    if (gbase < 1024) { xsrc = drone; Wp = wp0; bias = bq; }
    else              { xsrc = sat;   Wp = wp1; bias = bk; }

    s16x8 bvr[8][4];
#pragma unroll
    for (int kk = 0; kk < 8; kk++)
#pragma unroll
        for (int ni = 0; ni < 4; ni++)
            bvr[kk][ni] = *(const s16x8*)(Wp + ((size_t)((w * 4 + ni) * 8 + kk) * 64 + lane) * 8);

    float bcol[4];
#pragma unroll
    for (int ni = 0; ni < 4; ni++) bcol[ni] = bias[w * 64 + ni * 16 + l16];

#pragma unroll
    for (int gi = 0; gi < 4; gi++) {
        int g = gbase + gi;                    // group 0..2047
        int rsrc = (g < 1024) ? g * 16 : g * 16 - NROWS;

        {   // stage 16x256 f32 A-tile, coalesced
            int r = t >> 4, c0 = (t & 15) * 4;
            const float* gp = xsrc + (size_t)(rsrc + r) * DM;
#pragma unroll
            for (int jj = 0; jj < 4; jj++)
                *(f32x4*)&AB.As[r][c0 + jj * 64] = *(const f32x4*)(gp + c0 + jj * 64);
        }
        __syncthreads();

        f32x4 acc[4];
#pragma unroll
        for (int ni = 0; ni < 4; ni++) acc[ni] = f32x4{0.f, 0.f, 0.f, 0.f};
#pragma unroll
        for (int kk = 0; kk < 8; kk++) {
            int k0 = kk * 32 + lh * 8;
            f32x4 a0 = *(const f32x4*)&AB.As[l16][k0];
            f32x4 a1 = *(const f32x4*)&AB.As[l16][k0 + 4];
            s16x8 av;
#pragma unroll
            for (int jj = 0; jj < 4; jj++) {
                av[jj]     = (short)f2bf(a0[jj]);
                av[jj + 4] = (short)f2bf(a1[jj]);
            }
#pragma unroll
            for (int ni = 0; ni < 4; ni++)
                acc[ni] = __builtin_amdgcn_mfma_f32_16x16x32_bf16(av, bvr[kk][ni], acc[ni], 0, 0, 0);
        }
        float ssq[4] = {0.f, 0.f, 0.f, 0.f};
#pragma unroll
        for (int ni = 0; ni < 4; ni++) {
#pragma unroll
            for (int r = 0; r < 4; r++) {
                acc[ni][r] += bcol[ni];
                ssq[r] += acc[ni][r] * acc[ni][r];
            }
        }
#pragma unroll
        for (int off = 1; off < 16; off <<= 1)
#pragma unroll
            for (int r = 0; r < 4; r++) ssq[r] += __shfl_xor(ssq[r], off);
        if (l16 == 0)
#pragma unroll
            for (int r = 0; r < 4; r++) red[w][lh * 4 + r] = ssq[r];
        __syncthreads();

        float inv[4];
#pragma unroll
        for (int r = 0; r < 4; r++) {
            int row = lh * 4 + r;
            float tot = red[0][row] + red[1][row] + red[2][row] + red[3][row];
            inv[r] = 1.0f / fmaxf(sqrtf(tot), 1e-12f);
        }
#pragma unroll
        for (int ni = 0; ni < 4; ni++)
#pragma unroll
            for (int r = 0; r < 4; r++)
                AB.S[lh * 4 + r][w * 64 + ni * 16 + l16] = f2bf(acc[ni][r] * inv[r]);
        __syncthreads();
#pragma unroll
        for (int h = 0; h < 2; h++) {
            int kk = w + h * 4;
            s16x8 vv = *(const s16x8*)&AB.S[l16][kk * 32 + lh * 8];
            *(s16x8*)(qkp + ((size_t)(g * 8 + kk) * 64 + lane) * 8) = vv;
        }
        __syncthreads();
    }
}

// ---------------------------------------------------------------- P2: K~ GEMM
__global__ void __launch_bounds__(256) k_cost(const ushort* __restrict__ qkp,
                                              char* __restrict__ ktc, int kstride) {
    int t = threadIdx.x, lane = t & 63, w = t >> 6;
    int l16 = lane & 15, lh = lane >> 4;
    int x = blockIdx.x, xcd = x & 7;
    int tile = xcd * 128 + (x >> 3);             // b = tile>>6 = 2*xcd + ...
    int b = tile >> 6, ty = (tile >> 3) & 7, tx = tile & 7;
    int rg  = b * 64 + ty * 8 + (w >> 1) * 4;
    int cgp = 1024 + b * 64 + tx * 8 + (w & 1) * 4;
    f32x4 acc[4][4];
#pragma unroll
    for (int i = 0; i < 4; i++)
#pragma unroll
        for (int jj = 0; jj < 4; jj++) acc[i][jj] = f32x4{0.f, 0.f, 0.f, 0.f};
#pragma unroll
    for (int kk = 0; kk < 8; kk++) {
        s16x8 am[4], bn[4];
#pragma unroll
        for (int mi = 0; mi < 4; mi++)
            am[mi] = *(const s16x8*)(qkp + ((size_t)((rg + mi) * 8 + kk) * 64 + lane) * 8);
#pragma unroll
        for (int ni = 0; ni < 4; ni++)
            bn[ni] = *(const s16x8*)(qkp + ((size_t)((cgp + ni) * 8 + kk) * 64 + lane) * 8);
#pragma unroll
        for (int mi = 0; mi < 4; mi++)
#pragma unroll
            for (int ni = 0; ni < 4; ni++)
                acc[mi][ni] = __builtin_amdgcn_mfma_f32_16x16x32_bf16(
                    am[mi], bn[ni], acc[mi][ni], 0, 0, 0);
    }
    int rl = ty * 128 + (w >> 1) * 64, cl = tx * 128 + (w & 1) * 64;
#pragma unroll
    for (int mi = 0; mi < 4; mi++)
#pragma unroll
        for (int r = 0; r < 4; r++) {
            int row = rl + mi * 16 + lh * 4 + r;
            ushort* orow = (ushort*)(ktc + (size_t)(b * NQ + row) * (size_t)kstride);
#pragma unroll
            for (int ni = 0; ni < 4; ni++)
                orow[cl + ni * 16 + l16] =
                    f2bf(__expf(fmaf(RINV, acc[mi][ni][r], -RINV)));
        }
}

// ---------------------------------------------------------------- comb:
// b[i] = 1 / sum over 64 strips. 64 blocks x 256 thr; batch pinned to its XCD.
__global__ void __launch_bounds__(256) k_comb(const float* __restrict__ part,
                                              float* __restrict__ bvec) {
    int blk = blockIdx.x, t = threadIdx.x;
    int xcd = blk & 7, r = blk >> 3;             // r 0..7
    int batch = 2 * xcd + (r >> 2), quarter = r & 3;
    int m = quarter * 256 + t;
    const float* pb = part + (size_t)batch * 64 * NQ + m;
    float s = 0.f;
#pragma unroll 8
    for (int c = 0; c < 64; c++) s += pb[(size_t)c * NQ];
    bvec[batch * NQ + m] = 1.0f / s;
}

// ---------------------------------------------------------------- fused Sinkhorn iter:
// 1024 blocks x 256 thr (4 blocks/CU, 16 waves/CU), XCD-pinned
// (virtual bid = (x&7)*128 + x>>3; batch = bid>>6; 16-row chunk = bid&63).
// Reads finished b (4 KB) -- no per-block strip recombine.
template<int FIRST>
__global__ void __launch_bounds__(256) k_sink(const char* __restrict__ ktc, int kstride,
                                              const float* __restrict__ bvec,
                                              float* __restrict__ u,
                                              float* __restrict__ partout) {
    __shared__ float bsh[NQ];
    __shared__ float pcol[4][NQ];
    int t = threadIdx.x;
    int lane = t & 63, w = t >> 6;
    int x = blockIdx.x;
    int bid = (x & 7) * 128 + (x >> 3);          // virtual id 0..1023
    int b = bid >> 6, ch = bid & 63;

    if (FIRST) {
        *(f32x4*)&bsh[t * 4] = f32x4{1.f, 1.f, 1.f, 1.f};
    } else {
        *(f32x4*)&bsh[t * 4] = *(const f32x4*)(bvec + (b << 10) + t * 4);
    }
#pragma unroll
    for (int r = 0; r < 4; r++) *(f32x4*)&pcol[r][t * 4] = f32x4{0.f, 0.f, 0.f, 0.f};
    __syncthreads();

    float br0[8], br1[8];
#pragma unroll
    for (int jj = 0; jj < 8; jj++) {
        br0[jj] = bsh[lane * 8 + jj];
        br1[jj] = bsh[512 + lane * 8 + jj];
    }

    float pa0[8], pa1[8];
#pragma unroll
    for (int jj = 0; jj < 8; jj++) { pa0[jj] = 0.f; pa1[jj] = 0.f; }

    int rowbase = (b << 10) + ch * 16 + w * 4;   // 4 rows per wave
#pragma unroll
    for (int rp = 0; rp < 2; rp++) {             // 2 rows per strip for ILP
        const ushort* ra = (const ushort*)(ktc + (size_t)(rowbase + rp * 2) * (size_t)kstride);
        const ushort* rb = (const ushort*)(ktc + (size_t)(rowbase + rp * 2 + 1) * (size_t)kstride);
        s16x8 ka0 = *(const s16x8*)(ra + lane * 8);
        s16x8 ka1 = *(const s16x8*)(ra + 512 + lane * 8);
        s16x8 kb0 = *(const s16x8*)(rb + lane * 8);
        s16x8 kb1 = *(const s16x8*)(rb + 512 + lane * 8);
        float sa = 0.f, sb = 0.f;
#pragma unroll
        for (int jj = 0; jj < 8; jj++) {
            sa = fmaf(bf2f((ushort)ka0[jj]), br0[jj], sa);
            sa = fmaf(bf2f((ushort)ka1[jj]), br1[jj], sa);
            sb = fmaf(bf2f((ushort)kb0[jj]), br0[jj], sb);
            sb = fmaf(bf2f((ushort)kb1[jj]), br1[jj], sb);
        }
#pragma unroll
        for (int o = 32; o; o >>= 1) {
            sa += __shfl_xor(sa, o);
            sb += __shfl_xor(sb, o);
        }
        float aa = 1.0f / sa, ab = 1.0f / sb;
        if (lane == 0) {
            u[rowbase + rp * 2]     = aa;
            u[rowbase + rp * 2 + 1] = ab;
        }
#pragma unroll
        for (int jj = 0; jj < 8; jj++) {
            pa0[jj] = fmaf(bf2f((ushort)ka0[jj]), aa, pa0[jj]);
            pa0[jj] = fmaf(bf2f((ushort)kb0[jj]), ab, pa0[jj]);
            pa1[jj] = fmaf(bf2f((ushort)ka1[jj]), aa, pa1[jj]);
            pa1[jj] = fmaf(bf2f((ushort)kb1[jj]), ab, pa1[jj]);
        }
    }
#pragma unroll
    for (int jj = 0; jj < 8; jj++) {
        pcol[w][lane * 8 + jj]       = pa0[jj];
        pcol[w][512 + lane * 8 + jj] = pa1[jj];
    }
    __syncthreads();
    {
        f32x4 s = *(const f32x4*)&pcol[0][t * 4];
        s += *(const f32x4*)&pcol[1][t * 4];
        s += *(const f32x4*)&pcol[2][t * 4];
        s += *(const f32x4*)&pcol[3][t * 4];
        *(f32x4*)&partout[((size_t)b * 64 + ch) * NQ + t * 4] = s;
    }
}

// ---------------------------------------------------------------- final:
// 512 x 256 (proven shape): read combined b; plan = a*b*K~ (plain stores);
// ot partials. XCD-pinned.
__global__ void __launch_bounds__(256) k_final(const char* __restrict__ ktc, int kstride,
                                               const float* __restrict__ bvec,
                                               const float* __restrict__ u,
                                               float* __restrict__ out,
                                               float* __restrict__ bprt) {
    __shared__ float bsh[NQ];
    __shared__ float red[4];
    int t = threadIdx.x;
    int lane = t & 63, w = t >> 6;
    int x = blockIdx.x;
    int bid = (x & 7) * 64 + (x >> 3);
    int b = bid >> 5, ch = bid & 31;

    *(f32x4*)&bsh[t * 4] = *(const f32x4*)(bvec + (b << 10) + t * 4);
    __syncthreads();

    float br0[8], br1[8];
#pragma unroll
    for (int jj = 0; jj < 8; jj++) {
        br0[jj] = bsh[lane * 8 + jj];
        br1[jj] = bsh[512 + lane * 8 + jj];
    }
    float sacc = 0.f;
    int rowbase = (b << 10) + ch * 32 + w * 8;
#pragma unroll
    for (int rr = 0; rr < 8; rr++) {
        int row = rowbase + rr;
        const ushort* kr = (const ushort*)(ktc + (size_t)row * (size_t)kstride);
        s16x8 k0 = *(const s16x8*)(kr + lane * 8);
        s16x8 k1 = *(const s16x8*)(kr + 512 + lane * 8);
        float a = u[row];
        float* orow = out + (size_t)row * NQ;
        float pv0[8], pv1[8];
#pragma unroll
        for (int jj = 0; jj < 8; jj++) {
            float kf0 = bf2f((ushort)k0[jj]);
            float kf1 = bf2f((ushort)k1[jj]);
            float p0 = a * br0[jj] * kf0;
            float p1 = a * br1[jj] * kf1;
            sacc = fmaf(p0, -0.1f * __logf(kf0), sacc);
            sacc = fmaf(p1, -0.1f * __logf(kf1), sacc);
            pv0[jj] = p0; pv1[jj] = p1;
        }
        *(f32x4*)(orow + lane * 8)           = *(f32x4*)&pv0[0];
        *(f32x4*)(orow + lane * 8 + 4)       = *(f32x4*)&pv0[4];
        *(f32x4*)(orow + 512 + lane * 8)     = *(f32x4*)&pv1[0];
        *(f32x4*)(orow + 512 + lane * 8 + 4) = *(f32x4*)&pv1[4];
    }
#pragma unroll
    for (int o = 32; o; o >>= 1) sacc += __shfl_xor(sacc, o);
    if (lane == 0) red[w] = sacc;
    __syncthreads();
    if (t == 0) bprt[blockIdx.x] = red[0] + red[1] + red[2] + red[3];
}

__global__ void k_reduce(const float* __restrict__ bprt, float* __restrict__ out) {
    int t = threadIdx.x;
    float s = bprt[t] + bprt[t + 256];
#pragma unroll
    for (int o = 32; o; o >>= 1) s += __shfl_xor(s, o);
    __shared__ float sm[4];
    if ((t & 63) == 0) sm[t >> 6] = s;
    __syncthreads();
    if (t == 0)
        out[(size_t)BATCH * NQ * NQ] =
            (sm[0] + sm[1] + sm[2] + sm[3]) * (1.0f / BATCH);
}

// ---------------------------------------------------------------- launch
extern "C" void kernel_launch(void* const* d_in, const int* in_sizes, int n_in,
                              void* d_out, int out_size, void* d_ws, size_t ws_size,
                              hipStream_t stream) {
    const float* drone = (const float*)d_in[0];
    const float* sat   = (const float*)d_in[1];
    const float* Wq    = (const float*)d_in[2];
    const float* bq    = (const float*)d_in[3];
    const float* Wk    = (const float*)d_in[4];
    const float* bk    = (const float*)d_in[5];
    float* out = (float*)d_out;

    char* ws = (char*)d_ws;
    ushort* wp0   = (ushort*)ws;                 // 128 KB packed Wq
    ushort* wp1   = (ushort*)(ws + 131072);      // 128 KB packed Wk
    ushort* qkp   = (ushort*)(ws + 262144);      // 16 MB packed q|k
    float*  u     = (float*)(ws + 17039360);     // 64 KB: a potentials
    float*  bvec  = (float*)(ws + 17104896);     // 64 KB: combined b
    float*  part  = (float*)(ws + 17170432);     // 4 MB col partials [16][64][1024]
    float*  bprt  = (float*)(ws + 21364736);     // 2 KB block partials

    // K~ bf16 (32 MB): in ws if it fits (evidence: ws = 256 MiB), else
    // interleaved into d_out rows (row i bytes i*4096..+2048; per-lane
    // read-before-write makes k_final safe).
    char* ktc; int kstride;
    if (ws_size >= (size_t)55000000) { ktc = ws + 21368832; kstride = 2048; }
    else                             { ktc = (char*)d_out;  kstride = 4096; }

    k_prep<<<64, 256, 0, stream>>>(Wq, Wk, wp0, wp1);
    k_proj<<<512, 256, 0, stream>>>(drone, sat, wp0, wp1, bq, bk, qkp);
    k_cost<<<1024, 256, 0, stream>>>(qkp, ktc, kstride);

    k_sink<1><<<1024, 256, 0, stream>>>(ktc, kstride, bvec, u, part);   // it 1
    for (int it = 1; it < 5; it++) {
        k_comb<<<64, 256, 0, stream>>>(part, bvec);
        k_sink<0><<<1024, 256, 0, stream>>>(ktc, kstride, bvec, u, part);
    }
    k_comb<<<64, 256, 0, stream>>>(part, bvec);
    k_final<<<512, 256, 0, stream>>>(ktc, kstride, bvec, u, out, bprt);
    k_reduce<<<1, 256, 0, stream>>>(bprt, out);
}

// Round 16
// 113.518 us; speedup vs baseline: 1.1185x; 1.1185x over previous
//
#include <hip/hip_runtime.h>
#include <hip/hip_bf16.h>

// Sizes (fixed by the problem)
#define BATCH 16
#define NQ    1024
#define DM    256
#define NROWS (BATCH * NQ)   // 16384 rows per side
#define RINV  10.0f          // 1/REG

typedef float  f32x4 __attribute__((ext_vector_type(4)));
typedef short  s16x8 __attribute__((ext_vector_type(8)));

static __device__ __forceinline__ ushort f2bf(float f) {
    unsigned u = __builtin_bit_cast(unsigned, f);
    u += 0x7fffu + ((u >> 16) & 1u);
    return (ushort)(u >> 16);
}
static __device__ __forceinline__ float bf2f(ushort h) {
    return __builtin_bit_cast(float, ((unsigned)h) << 16);
}

// Linear-domain Sinkhorn on K~ = exp(-10*cost) stored bf16 (33.5 MB):
//   a = 1/(K~ b),  b = 1/(K~^T a),  plan = a*b*K~,  cost = -0.1*log(K~).
// FINAL CONFIG = round-14 winner (113.9us), exact revert:
//  - fragment-packed W and q/k (1KB coalesced wave loads)
//  - XCD-pinned batches (block i -> XCD i%8; batches {2xcd,2xcd+1} on xcd
//    across proj/cost/sink/final -> K~ + partials L2-resident cross-launch)
//  - W fragments hoisted to registers in proj (4 row-groups/block)
//  - fused sink (a-update + b-col-partials in one K~ pass), 512x256, 32
//    partial strips, ping-pong buffers
// Measured dead ends (do NOT reintroduce):
//  - cooperative launch: silently fails in this harness (R3/R4)
//  - device fences/atomics in hot kernels: +25us (R8)
//  - non-temporal plan stores: +14us (R10 A/B)
//  - >256-thr blocks for short streaming kernels: +5-8us (R8-R10)
//  - comb-split (more, smaller dispatches): +13us (R15)

// ---------------------------------------------------------------- P0: pack W
__global__ void __launch_bounds__(256) k_prep(const float* __restrict__ Wq,
                                              const float* __restrict__ Wk,
                                              ushort* __restrict__ wp0,
                                              ushort* __restrict__ wp1) {
    int gid = blockIdx.x * 256 + threadIdx.x;   // 64 blocks -> gid < 16384
    const float* Wsrc = (gid < 8192) ? Wq : Wk;
    ushort* dst = (gid < 8192) ? wp0 : wp1;
    int gx = gid & 8191;
    int gcol = gx >> 9, kk = (gx >> 6) & 7, ln = gx & 63;
    const float* srow = Wsrc + (size_t)(gcol * 16 + (ln & 15)) * DM
                             + kk * 32 + (ln >> 4) * 8;
    ushort* d = dst + (size_t)gx * 8;
#pragma unroll
    for (int e = 0; e < 8; e++) d[e] = f2bf(srow[e]);
}

// ---------------------------------------------------------------- P1: projection
// 512 blocks x 256 thr; 4 x 16-row groups per block; W fragments hoisted to
// registers. XCD pinning: batches {2xcd, 2xcd+1} on XCD xcd.
__global__ void __launch_bounds__(256) k_proj(
        const float* __restrict__ drone, const float* __restrict__ sat,
        const ushort* __restrict__ wp0, const ushort* __restrict__ wp1,
        const float* __restrict__ bq, const float* __restrict__ bk,
        ushort* __restrict__ qkp) {
    __shared__ union {
        float  As[16][260];
        ushort S[16][280];
    } AB;
    __shared__ float red[4][16];

    int t = threadIdx.x;
    int lane = t & 63, w = t >> 6, l16 = lane & 15, lh = lane >> 4;
    int x = blockIdx.x, xcd = x & 7, j = x >> 3;      // j 0..63
    int gbase = (j < 32) ? (xcd * 128 + j * 4)
                         : (1024 + xcd * 128 + (j - 32) * 4);
    const float* xsrc; const ushort* Wp; const float* bias;
    if (gbase < 1024) { xsrc = drone; Wp = wp0; bias = bq; }
    else              { xsrc = sat;   Wp = wp1; bias = bk; }

    // hoist this wave's W fragments: [kk][ni] -> 128 VGPR, reused over 4 groups
    s16x8 bvr[8][4];
#pragma unroll
    for (int kk = 0; kk < 8; kk++)
#pragma unroll
        for (int ni = 0; ni < 4; ni++)
            bvr[kk][ni] = *(const s16x8*)(Wp + ((size_t)((w * 4 + ni) * 8 + kk) * 64 + lane) * 8);

    float bcol[4];
#pragma unroll
    for (int ni = 0; ni < 4; ni++) bcol[ni] = bias[w * 64 + ni * 16 + l16];

#pragma unroll
    for (int gi = 0; gi < 4; gi++) {
        int g = gbase + gi;                    // group 0..2047
        int rsrc = (g < 1024) ? g * 16 : g * 16 - NROWS;

        {   // stage 16x256 f32 A-tile, coalesced
            int r = t >> 4, c0 = (t & 15) * 4;
            const float* gp = xsrc + (size_t)(rsrc + r) * DM;
#pragma unroll
            for (int jj = 0; jj < 4; jj++)
                *(f32x4*)&AB.As[r][c0 + jj * 64] = *(const f32x4*)(gp + c0 + jj * 64);
        }
        __syncthreads();

        f32x4 acc[4];
#pragma unroll
        for (int ni = 0; ni < 4; ni++) acc[ni] = f32x4{0.f, 0.f, 0.f, 0.f};
#pragma unroll
        for (int kk = 0; kk < 8; kk++) {
            int k0 = kk * 32 + lh * 8;
            f32x4 a0 = *(const f32x4*)&AB.As[l16][k0];
            f32x4 a1 = *(const f32x4*)&AB.As[l16][k0 + 4];
            s16x8 av;
#pragma unroll
            for (int jj = 0; jj < 4; jj++) {
                av[jj]     = (short)f2bf(a0[jj]);
                av[jj + 4] = (short)f2bf(a1[jj]);
            }
#pragma unroll
            for (int ni = 0; ni < 4; ni++)
                acc[ni] = __builtin_amdgcn_mfma_f32_16x16x32_bf16(av, bvr[kk][ni], acc[ni], 0, 0, 0);
        }
        float ssq[4] = {0.f, 0.f, 0.f, 0.f};
#pragma unroll
        for (int ni = 0; ni < 4; ni++) {
#pragma unroll
            for (int r = 0; r < 4; r++) {
                acc[ni][r] += bcol[ni];
                ssq[r] += acc[ni][r] * acc[ni][r];
            }
        }
#pragma unroll
        for (int off = 1; off < 16; off <<= 1)
#pragma unroll
            for (int r = 0; r < 4; r++) ssq[r] += __shfl_xor(ssq[r], off);
        if (l16 == 0)
#pragma unroll
            for (int r = 0; r < 4; r++) red[w][lh * 4 + r] = ssq[r];
        __syncthreads();   // red visible; all As reads done before S overwrite

        float inv[4];
#pragma unroll
        for (int r = 0; r < 4; r++) {
            int row = lh * 4 + r;
            float tot = red[0][row] + red[1][row] + red[2][row] + red[3][row];
            inv[r] = 1.0f / fmaxf(sqrtf(tot), 1e-12f);
        }
#pragma unroll
        for (int ni = 0; ni < 4; ni++)
#pragma unroll
            for (int r = 0; r < 4; r++)
                AB.S[lh * 4 + r][w * 64 + ni * 16 + l16] = f2bf(acc[ni][r] * inv[r]);
        __syncthreads();
#pragma unroll
        for (int h = 0; h < 2; h++) {
            int kk = w + h * 4;
            s16x8 vv = *(const s16x8*)&AB.S[l16][kk * 32 + lh * 8];
            *(s16x8*)(qkp + ((size_t)(g * 8 + kk) * 64 + lane) * 8) = vv;
        }
        __syncthreads();   // all S reads done before next gi restages As
    }
}

// ---------------------------------------------------------------- P2: K~ GEMM
// XCD swizzle: tiles of batches 2xcd,2xcd+1 on XCD xcd.
__global__ void __launch_bounds__(256) k_cost(const ushort* __restrict__ qkp,
                                              char* __restrict__ ktc, int kstride) {
    int t = threadIdx.x, lane = t & 63, w = t >> 6;
    int l16 = lane & 15, lh = lane >> 4;
    int x = blockIdx.x, xcd = x & 7;
    int tile = xcd * 128 + (x >> 3);             // b = tile>>6 = 2*xcd + ...
    int b = tile >> 6, ty = (tile >> 3) & 7, tx = tile & 7;
    int rg  = b * 64 + ty * 8 + (w >> 1) * 4;
    int cgp = 1024 + b * 64 + tx * 8 + (w & 1) * 4;
    f32x4 acc[4][4];
#pragma unroll
    for (int i = 0; i < 4; i++)
#pragma unroll
        for (int jj = 0; jj < 4; jj++) acc[i][jj] = f32x4{0.f, 0.f, 0.f, 0.f};
#pragma unroll
    for (int kk = 0; kk < 8; kk++) {
        s16x8 am[4], bn[4];
#pragma unroll
        for (int mi = 0; mi < 4; mi++)
            am[mi] = *(const s16x8*)(qkp + ((size_t)((rg + mi) * 8 + kk) * 64 + lane) * 8);
#pragma unroll
        for (int ni = 0; ni < 4; ni++)
            bn[ni] = *(const s16x8*)(qkp + ((size_t)((cgp + ni) * 8 + kk) * 64 + lane) * 8);
#pragma unroll
        for (int mi = 0; mi < 4; mi++)
#pragma unroll
            for (int ni = 0; ni < 4; ni++)
                acc[mi][ni] = __builtin_amdgcn_mfma_f32_16x16x32_bf16(
                    am[mi], bn[ni], acc[mi][ni], 0, 0, 0);
    }
    int rl = ty * 128 + (w >> 1) * 64, cl = tx * 128 + (w & 1) * 64;
#pragma unroll
    for (int mi = 0; mi < 4; mi++)
#pragma unroll
        for (int r = 0; r < 4; r++) {
            int row = rl + mi * 16 + lh * 4 + r;
            ushort* orow = (ushort*)(ktc + (size_t)(b * NQ + row) * (size_t)kstride);
#pragma unroll
            for (int ni = 0; ni < 4; ni++)
                orow[cl + ni * 16 + l16] =
                    f2bf(__expf(fmaf(RINV, acc[mi][ni][r], -RINV)));
        }
}

// ---------------------------------------------------------------- fused Sinkhorn iter:
// 512 blocks x 256 thr, XCD-pinned (virtual bid = (x&7)*64 + x>>3).
template<int FIRST>
__global__ void __launch_bounds__(256) k_sink(const char* __restrict__ ktc, int kstride,
                                              const float* __restrict__ partin,
                                              float* __restrict__ u,
                                              float* __restrict__ partout) {
    __shared__ float bsh[NQ];
    __shared__ float pcol[4][NQ];
    int t = threadIdx.x;
    int lane = t & 63, w = t >> 6;
    int x = blockIdx.x;
    int bid = (x & 7) * 64 + (x >> 3);           // virtual id, batch = bid>>5
    int b = bid >> 5, ch = bid & 31;

    if (FIRST) {
        *(f32x4*)&bsh[t * 4] = f32x4{1.f, 1.f, 1.f, 1.f};
    } else {
        f32x4 s = f32x4{0.f, 0.f, 0.f, 0.f};
        const float* pb = partin + (size_t)b * 32 * NQ + t * 4;
#pragma unroll 8
        for (int c = 0; c < 32; c++)
            s += *(const f32x4*)(pb + (size_t)c * NQ);
        f32x4 r;
#pragma unroll
        for (int jj = 0; jj < 4; jj++) r[jj] = 1.0f / s[jj];
        *(f32x4*)&bsh[t * 4] = r;
    }
#pragma unroll
    for (int r = 0; r < 4; r++) *(f32x4*)&pcol[r][t * 4] = f32x4{0.f, 0.f, 0.f, 0.f};
    __syncthreads();

    float br0[8], br1[8];
#pragma unroll
    for (int jj = 0; jj < 8; jj++) {
        br0[jj] = bsh[lane * 8 + jj];
        br1[jj] = bsh[512 + lane * 8 + jj];
    }

    float pa0[8], pa1[8];
#pragma unroll
    for (int jj = 0; jj < 8; jj++) { pa0[jj] = 0.f; pa1[jj] = 0.f; }

    int rowbase = (b << 10) + ch * 32 + w * 8;   // 8 rows per wave
#pragma unroll
    for (int rp = 0; rp < 4; rp++) {             // 2 rows per strip for ILP
        const ushort* ra = (const ushort*)(ktc + (size_t)(rowbase + rp * 2) * (size_t)kstride);
        const ushort* rb = (const ushort*)(ktc + (size_t)(rowbase + rp * 2 + 1) * (size_t)kstride);
        s16x8 ka0 = *(const s16x8*)(ra + lane * 8);
        s16x8 ka1 = *(const s16x8*)(ra + 512 + lane * 8);
        s16x8 kb0 = *(const s16x8*)(rb + lane * 8);
        s16x8 kb1 = *(const s16x8*)(rb + 512 + lane * 8);
        float sa = 0.f, sb = 0.f;
#pragma unroll
        for (int jj = 0; jj < 8; jj++) {
            sa = fmaf(bf2f((ushort)ka0[jj]), br0[jj], sa);
            sa = fmaf(bf2f((ushort)ka1[jj]), br1[jj], sa);
            sb = fmaf(bf2f((ushort)kb0[jj]), br0[jj], sb);
            sb = fmaf(bf2f((ushort)kb1[jj]), br1[jj], sb);
        }
#pragma unroll
        for (int o = 32; o; o >>= 1) {
            sa += __shfl_xor(sa, o);
            sb += __shfl_xor(sb, o);
        }
        float aa = 1.0f / sa, ab = 1.0f / sb;
        if (lane == 0) {
            u[rowbase + rp * 2]     = aa;
            u[rowbase + rp * 2 + 1] = ab;
        }
#pragma unroll
        for (int jj = 0; jj < 8; jj++) {
            pa0[jj] = fmaf(bf2f((ushort)ka0[jj]), aa, pa0[jj]);
            pa0[jj] = fmaf(bf2f((ushort)kb0[jj]), ab, pa0[jj]);
            pa1[jj] = fmaf(bf2f((ushort)ka1[jj]), aa, pa1[jj]);
            pa1[jj] = fmaf(bf2f((ushort)kb1[jj]), ab, pa1[jj]);
        }
    }
#pragma unroll
    for (int jj = 0; jj < 8; jj++) {
        pcol[w][lane * 8 + jj]       = pa0[jj];
        pcol[w][512 + lane * 8 + jj] = pa1[jj];
    }
    __syncthreads();
    {
        f32x4 s = *(const f32x4*)&pcol[0][t * 4];
        s += *(const f32x4*)&pcol[1][t * 4];
        s += *(const f32x4*)&pcol[2][t * 4];
        s += *(const f32x4*)&pcol[3][t * 4];
        *(f32x4*)&partout[((size_t)b * 32 + ch) * NQ + t * 4] = s;
    }
}

// ---------------------------------------------------------------- final:
// recombine b; plan = a*b*K~ (plain stores); ot partials. XCD-pinned.
__global__ void __launch_bounds__(256) k_final(const char* __restrict__ ktc, int kstride,
                                               const float* __restrict__ partin,
                                               const float* __restrict__ u,
                                               float* __restrict__ out,
                                               float* __restrict__ bprt) {
    __shared__ float bsh[NQ];
    __shared__ float red[4];
    int t = threadIdx.x;
    int lane = t & 63, w = t >> 6;
    int x = blockIdx.x;
    int bid = (x & 7) * 64 + (x >> 3);
    int b = bid >> 5, ch = bid & 31;
    {
        f32x4 s = f32x4{0.f, 0.f, 0.f, 0.f};
        const float* pb = partin + (size_t)b * 32 * NQ + t * 4;
#pragma unroll 8
        for (int c = 0; c < 32; c++)
            s += *(const f32x4*)(pb + (size_t)c * NQ);
        f32x4 r;
#pragma unroll
        for (int jj = 0; jj < 4; jj++) r[jj] = 1.0f / s[jj];
        *(f32x4*)&bsh[t * 4] = r;
    }
    __syncthreads();

    float br0[8], br1[8];
#pragma unroll
    for (int jj = 0; jj < 8; jj++) {
        br0[jj] = bsh[lane * 8 + jj];
        br1[jj] = bsh[512 + lane * 8 + jj];
    }
    float sacc = 0.f;
    int rowbase = (b << 10) + ch * 32 + w * 8;
#pragma unroll
    for (int rr = 0; rr < 8; rr++) {
        int row = rowbase + rr;
        const ushort* kr = (const ushort*)(ktc + (size_t)row * (size_t)kstride);
        s16x8 k0 = *(const s16x8*)(kr + lane * 8);
        s16x8 k1 = *(const s16x8*)(kr + 512 + lane * 8);
        float a = u[row];
        float* orow = out + (size_t)row * NQ;
        float pv0[8], pv1[8];
#pragma unroll
        for (int jj = 0; jj < 8; jj++) {
            float kf0 = bf2f((ushort)k0[jj]);
            float kf1 = bf2f((ushort)k1[jj]);
            float p0 = a * br0[jj] * kf0;
            float p1 = a * br1[jj] * kf1;
            sacc = fmaf(p0, -0.1f * __logf(kf0), sacc);
            sacc = fmaf(p1, -0.1f * __logf(kf1), sacc);
            pv0[jj] = p0; pv1[jj] = p1;
        }
        *(f32x4*)(orow + lane * 8)           = *(f32x4*)&pv0[0];
        *(f32x4*)(orow + lane * 8 + 4)       = *(f32x4*)&pv0[4];
        *(f32x4*)(orow + 512 + lane * 8)     = *(f32x4*)&pv1[0];
        *(f32x4*)(orow + 512 + lane * 8 + 4) = *(f32x4*)&pv1[4];
    }
#pragma unroll
    for (int o = 32; o; o >>= 1) sacc += __shfl_xor(sacc, o);
    if (lane == 0) red[w] = sacc;
    __syncthreads();
    if (t == 0) bprt[blockIdx.x] = red[0] + red[1] + red[2] + red[3];
}

__global__ void k_reduce(const float* __restrict__ bprt, float* __restrict__ out) {
    int t = threadIdx.x;
    float s = bprt[t] + bprt[t + 256];
#pragma unroll
    for (int o = 32; o; o >>= 1) s += __shfl_xor(s, o);
    __shared__ float sm[4];
    if ((t & 63) == 0) sm[t >> 6] = s;
    __syncthreads();
    if (t == 0)
        out[(size_t)BATCH * NQ * NQ] =
            (sm[0] + sm[1] + sm[2] + sm[3]) * (1.0f / BATCH);
}

// ---------------------------------------------------------------- launch
extern "C" void kernel_launch(void* const* d_in, const int* in_sizes, int n_in,
                              void* d_out, int out_size, void* d_ws, size_t ws_size,
                              hipStream_t stream) {
    const float* drone = (const float*)d_in[0];
    const float* sat   = (const float*)d_in[1];
    const float* Wq    = (const float*)d_in[2];
    const float* bq    = (const float*)d_in[3];
    const float* Wk    = (const float*)d_in[4];
    const float* bk    = (const float*)d_in[5];
    float* out = (float*)d_out;

    char* ws = (char*)d_ws;
    ushort* wp0   = (ushort*)ws;                 // 128 KB packed Wq
    ushort* wp1   = (ushort*)(ws + 131072);      // 128 KB packed Wk
    ushort* qkp   = (ushort*)(ws + 262144);      // 16 MB packed q|k
    float*  u     = (float*)(ws + 17039360);     // 64 KB: a potentials
    float*  partA = (float*)(ws + 17104896);     // 2 MB col partials [16][32][1024]
    float*  partB = (float*)(ws + 19202048);     // 2 MB ping-pong
    float*  bprt  = (float*)(ws + 21299200);     // 2 KB block partials

    // K~ bf16 (32 MB): in ws if it fits (evidence: ws = 256 MiB), else
    // interleaved into d_out rows (row i bytes i*4096..+2048; per-lane
    // read-before-write makes k_final safe).
    char* ktc; int kstride;
    if (ws_size >= (size_t)54000000) { ktc = ws + 21303296; kstride = 2048; }
    else                             { ktc = (char*)d_out;  kstride = 4096; }

    k_prep<<<64, 256, 0, stream>>>(Wq, Wk, wp0, wp1);
    k_proj<<<512, 256, 0, stream>>>(drone, sat, wp0, wp1, bq, bk, qkp);
    k_cost<<<1024, 256, 0, stream>>>(qkp, ktc, kstride);

    k_sink<1><<<512, 256, 0, stream>>>(ktc, kstride, nullptr, u, partA);  // it 1
    k_sink<0><<<512, 256, 0, stream>>>(ktc, kstride, partA, u, partB);    // it 2
    k_sink<0><<<512, 256, 0, stream>>>(ktc, kstride, partB, u, partA);    // it 3
    k_sink<0><<<512, 256, 0, stream>>>(ktc, kstride, partA, u, partB);    // it 4
    k_sink<0><<<512, 256, 0, stream>>>(ktc, kstride, partB, u, partA);    // it 5

    k_final<<<512, 256, 0, stream>>>(ktc, kstride, partA, u, out, bprt);
    k_reduce<<<1, 256, 0, stream>>>(bprt, out);
}